// Round 6
// baseline (519.460 us; speedup 1.0000x reference)
//
#include <hip/hip_runtime.h>

// ============================================================================
// GAT classifier, N=8192. Softmax cancels the source term:
//   Z = (A @ (u*H)) / (A @ u),  u = exp(H @ a_dst).
// Round 6: overhead-trim round.
//  - wsetup fused into xw1m (W1^T fragments built in LDS per block).
//  - attn ksplit 8 (halves nump traffic; 4 blocks/CU).
//  - ep1: 1024x256, 2 nodes/wave, float4 LDS broadcasts; 8-node Gt2 writer.
//  - pack: 2048 blocks, 1 row/wave. ep2: 256 blocks; gpart 64 KB.
// ============================================================================

#define NN 8192

typedef __attribute__((ext_vector_type(8))) short s16x8;   // 8 bf16 (4 VGPR)
typedef __attribute__((ext_vector_type(4))) float f32x4;   // MFMA C/D
union V16 { uint4 u; s16x8 s; };

// ---- workspace layout ----
static constexpr size_t OFF_WBITS = 0;                                  // 8 MB bitmask
static constexpr size_t OFF_GT1H  = (size_t)8 << 20;                    // 1 MB Gt1 hi (tiled)
static constexpr size_t OFF_GT1L  = (size_t)9 << 20;                    // 1 MB Gt1 lo
static constexpr size_t OFF_U1    = (size_t)10 << 20;
static constexpr size_t OFF_DEN1  = ((size_t)10 << 20) + 32 * 1024;
static constexpr size_t OFF_GT2H  = ((size_t)10 << 20) + 128 * 1024;    // 768 KB Gt2 hi (tiled, M=48)
static constexpr size_t OFF_GT2L  = ((size_t)10 << 20) + 896 * 1024;    // 768 KB Gt2 lo
static constexpr size_t OFF_GPART = ((size_t)11 << 20) + 768 * 1024;    // 64 KB
static constexpr size_t OFF_NUMP  = (size_t)12 << 20;                   // 16 MB partials
static constexpr size_t OFF_DP    = (size_t)45 << 20;                   // 8 MB xw1 partials

__device__ __forceinline__ float elu_f(float x) {
    return x > 0.f ? x : expm1f(x);
}
__device__ __forceinline__ unsigned int bf16_rne(float x) {
    unsigned int u = __float_as_uint(x);
    return (u + 0x7FFFu + ((u >> 16) & 1u)) >> 16;
}
// pack (hi<<16)|lo where x ~= bf16(hi) + bf16(lo)
__device__ __forceinline__ unsigned int split_pack(float g) {
    unsigned int hi = bf16_rne(g);
    float fhi = __uint_as_float(hi << 16);
    unsigned int lo = bf16_rne(g - fhi);
    return (hi << 16) | lo;
}
__device__ __forceinline__ void split3(float f, unsigned int& h, unsigned int& m,
                                       unsigned int& l) {
    h = bf16_rne(f);
    float fh = __uint_as_float(h << 16);
    float r1 = f - fh;
    m = bf16_rne(r1);
    float fm = __uint_as_float(m << 16);
    l = bf16_rne(r1 - fm);
}
// 2 adjacency bits -> uint of 2 packed bf16 {0,1}
__device__ __forceinline__ unsigned int bits2bf(unsigned int b2) {
    return (b2 & 1u) * 0x3F80u + (b2 & 2u) * 0x1FC00000u;
}

// ---------------------------------------------------------------------------
// K1: H1 = X @ W1 on MFMA. W1^T fragments built in LDS per block (fused
// wsetup). grid (128 node-groups of 64, 4 ksplits of 192 k). Wave = n-tile.
// B = X rows split 3-way bf16; 5 MFMA terms.
// ---------------------------------------------------------------------------
__global__ __launch_bounds__(256) void k_xw1m(const float* __restrict__ X,
                                              const float* __restrict__ W1,
                                              float* __restrict__ Dp) {
    __shared__ unsigned int fh[6144];   // 24 KB: 4mt x 6kt x 64 lanes x uint4
    __shared__ unsigned int fl[6144];   // 24 KB
    const int tid = threadIdx.x, wv = tid >> 6, lane = tid & 63;
    const int ks = blockIdx.y;
    // ---- stage W1^T fragments ----
    for (int i = tid; i < 6144; i += 256) {
        const int feat = i & 63, kp = i >> 6;       // kp 0..95 (k-pairs)
        const int kg = ks * 192 + 2 * kp;
        float w0 = W1[(size_t)kg * 64 + feat];
        float w1 = W1[(size_t)(kg + 1) * 64 + feat];
        unsigned int h0 = bf16_rne(w0);
        unsigned int l0 = bf16_rne(w0 - __uint_as_float(h0 << 16));
        unsigned int h1 = bf16_rne(w1);
        unsigned int l1 = bf16_rne(w1 - __uint_as_float(h1 << 16));
        const int mt = feat >> 4, n = feat & 15;
        const int ktl = kp >> 4, rem = kp & 15, quad = rem >> 2, q = rem & 3;
        const int idx = ((mt * 6 + ktl) * 64 + quad * 16 + n) * 4 + q;
        fh[idx] = h0 | (h1 << 16);
        fl[idx] = l0 | (l1 << 16);
    }
    __syncthreads();
    const int n = lane & 15, quad = lane >> 4;
    const int node = blockIdx.x * 64 + wv * 16 + n;
    const int ntg = blockIdx.x * 4 + wv;
    f32x4 acc[4];
#pragma unroll
    for (int mt = 0; mt < 4; ++mt) acc[mt] = (f32x4){0.f, 0.f, 0.f, 0.f};
    const float4* X4 = (const float4*)X;
    for (int kk = 0; kk < 6; ++kk) {
        const int ktg = ks * 6 + kk;
        float4 x01 = X4[(size_t)node * 192 + ktg * 8 + quad * 2];
        float4 x23 = X4[(size_t)node * 192 + ktg * 8 + quad * 2 + 1];
        float xf[8] = {x01.x, x01.y, x01.z, x01.w, x23.x, x23.y, x23.z, x23.w};
        V16 bh, bm, bl;
        unsigned int* bhp = (unsigned int*)&bh.u;
        unsigned int* bmp = (unsigned int*)&bm.u;
        unsigned int* blp = (unsigned int*)&bl.u;
#pragma unroll
        for (int q = 0; q < 4; ++q) {
            unsigned int h0, m0, l0, h1, m1, l1;
            split3(xf[2 * q], h0, m0, l0);
            split3(xf[2 * q + 1], h1, m1, l1);
            bhp[q] = h0 | (h1 << 16);
            bmp[q] = m0 | (m1 << 16);
            blp[q] = l0 | (l1 << 16);
        }
#pragma unroll
        for (int mt = 0; mt < 4; ++mt) {
            const int base = ((mt * 6 + kk) * 64 + lane) * 4;
            V16 awh, awl;
            awh.u = *(const uint4*)&fh[base];
            awl.u = *(const uint4*)&fl[base];
            acc[mt] = __builtin_amdgcn_mfma_f32_16x16x32_bf16(awh.s, bh.s, acc[mt], 0, 0, 0);
            acc[mt] = __builtin_amdgcn_mfma_f32_16x16x32_bf16(awh.s, bm.s, acc[mt], 0, 0, 0);
            acc[mt] = __builtin_amdgcn_mfma_f32_16x16x32_bf16(awh.s, bl.s, acc[mt], 0, 0, 0);
            acc[mt] = __builtin_amdgcn_mfma_f32_16x16x32_bf16(awl.s, bh.s, acc[mt], 0, 0, 0);
            acc[mt] = __builtin_amdgcn_mfma_f32_16x16x32_bf16(awl.s, bm.s, acc[mt], 0, 0, 0);
        }
    }
#pragma unroll
    for (int mt = 0; mt < 4; ++mt)
        *(f32x4*)&Dp[(size_t)(((ks * 4 + mt) * 512 + ntg) * 64 + lane) * 4] = acc[mt];
}

// ---------------------------------------------------------------------------
// K1b: reduce Dp ksplits -> H1; u1 = exp(H1 @ a1[64:]); write Gt1 tiled + u1.
// ---------------------------------------------------------------------------
__global__ __launch_bounds__(256) void k_xcomb(const float* __restrict__ Dp,
                                               const float* __restrict__ a1,
                                               unsigned int* __restrict__ Gt1h,
                                               unsigned int* __restrict__ Gt1l,
                                               float* __restrict__ u1) {
    __shared__ float Hsh[64][33];
    __shared__ float us[32];
    const int tid = threadIdx.x;
    if (tid < 128) {
        const int ntl = tid >> 6, lane = tid & 63;
        const int n = lane & 15, quad = lane >> 4;
        const int ntg = blockIdx.x * 2 + ntl;
        float dpart = 0.f;
#pragma unroll
        for (int mt = 0; mt < 4; ++mt) {
            float v[4] = {0.f, 0.f, 0.f, 0.f};
#pragma unroll
            for (int ksp = 0; ksp < 4; ++ksp) {
                const float* p = &Dp[(size_t)(((ksp * 4 + mt) * 512 + ntg) * 64 + lane) * 4];
                v[0] += p[0]; v[1] += p[1]; v[2] += p[2]; v[3] += p[3];
            }
#pragma unroll
            for (int r = 0; r < 4; ++r) {
                int feat = mt * 16 + quad * 4 + r;
                Hsh[feat][ntl * 16 + n] = v[r];
                dpart += v[r] * a1[64 + feat];
            }
        }
        dpart += __shfl_xor(dpart, 16);
        dpart += __shfl_xor(dpart, 32);
        float uu = expf(dpart);
        if (lane < 16) {
            us[ntl * 16 + lane] = uu;
            u1[blockIdx.x * 32 + ntl * 16 + lane] = uu;
        }
    }
    __syncthreads();
    {
        const int mt = tid >> 6, lane = tid & 63;
        const int feat = mt * 16 + (lane & 15), quad = lane >> 4;
        uint4 hv, lv;
        unsigned int g0, g1;
#define PACK_Q(Q, FX)                                                   \
        {                                                               \
            int j0 = quad * 8 + 2 * Q;                                  \
            g0 = split_pack(us[j0] * Hsh[feat][j0]);                    \
            g1 = split_pack(us[j0 + 1] * Hsh[feat][j0 + 1]);            \
            hv.FX = (g0 >> 16) | (g1 & 0xFFFF0000u);                    \
            lv.FX = (g0 & 0xFFFFu) | (g1 << 16);                        \
        }
        PACK_Q(0, x) PACK_Q(1, y) PACK_Q(2, z) PACK_Q(3, w)
#undef PACK_Q
        size_t base = ((size_t)(mt * 256 + blockIdx.x) * 64 + lane) * 4;
        *(uint4*)(Gt1h + base) = hv;
        *(uint4*)(Gt1l + base) = lv;
    }
}

// ---------------------------------------------------------------------------
// K2: pack A -> bitmask + den1 = A @ u1. 2048 blocks; wave = 1 row.
// A read from HBM exactly once, 16B/lane.
// ---------------------------------------------------------------------------
__global__ __launch_bounds__(256) void k_pack(const int* __restrict__ A,
                                              const float* __restrict__ u1,
                                              unsigned int* __restrict__ Wb32,
                                              float* __restrict__ den1) {
    __shared__ unsigned short msh[4][512];
    const int tid = threadIdx.x, wv = tid >> 6, lane = tid & 63;
    const int row0 = blockIdx.x * 4;
    const int row = row0 + wv;
    float dsum = 0.f;
    for (int c = 0; c < 8; ++c) {
        const int j = c * 1024 + lane * 16;
        const int4* A0 = (const int4*)(A + (size_t)row * NN + j);
        const float4* U4 = (const float4*)(u1 + j);
        int4 a0 = A0[0], a1 = A0[1], a2 = A0[2], a3 = A0[3];
        float4 u0 = U4[0], u4 = U4[1], u8 = U4[2], uc = U4[3];
        unsigned int m0 = 0;
#define DO4(AV, UV, SH)                                                \
        m0 |= ((AV.x != 0) << (SH)) | ((AV.y != 0) << (SH + 1)) |      \
              ((AV.z != 0) << (SH + 2)) | ((AV.w != 0) << (SH + 3));   \
        dsum += (AV.x != 0 ? UV.x : 0.f) + (AV.y != 0 ? UV.y : 0.f) +  \
                (AV.z != 0 ? UV.z : 0.f) + (AV.w != 0 ? UV.w : 0.f);
        DO4(a0, u0, 0) DO4(a1, u4, 4) DO4(a2, u8, 8) DO4(a3, uc, 12)
#undef DO4
        msh[wv][c * 64 + lane] = (unsigned short)m0;
    }
#pragma unroll
    for (int off = 32; off; off >>= 1) dsum += __shfl_down(dsum, off);
    if (lane == 0) den1[row] = dsum;
    __syncthreads();
    {
        const int r = tid >> 6, i = tid & 63;
        const uint4* src = (const uint4*)&msh[r][0];
        uint4* dst = (uint4*)(Wb32 + (size_t)(row0 + r) * 256);
        dst[i] = src[i];
    }
}

// ---------------------------------------------------------------------------
// K3: layer-1 MFMA. grid (128 node-groups, 8 ksplits of 1024). WAVE = M-TILE.
// ---------------------------------------------------------------------------
__global__ __launch_bounds__(256) void k_attn1(const unsigned int* __restrict__ Wb32,
                                               const unsigned int* __restrict__ Gt1h,
                                               const unsigned int* __restrict__ Gt1l,
                                               float* __restrict__ num1p) {
    __shared__ unsigned int bw[64 * 36];    // 64 rows x 32 u32, stride 36
    const int tid = threadIdx.x, wv = tid >> 6, lane = tid & 63;
    const int node0 = blockIdx.x * 64;
    const int kt0 = blockIdx.y * 32;
    {
        const int r = tid >> 2, part = tid & 3;
        const uint4* src = (const uint4*)(Wb32 + (size_t)(node0 + r) * 256 + kt0 + part * 8);
        uint4 v0 = src[0], v1 = src[1];
        *(uint4*)&bw[r * 36 + part * 8] = v0;
        *(uint4*)&bw[r * 36 + part * 8 + 4] = v1;
    }
    __syncthreads();
    const int n = lane & 15, quad = lane >> 4;
    const int mt = wv;
    f32x4 acc[4];
#pragma unroll
    for (int nt = 0; nt < 4; ++nt) acc[nt] = (f32x4){0.f, 0.f, 0.f, 0.f};
#pragma unroll 4
    for (int ks = 0; ks < 32; ++ks) {
        size_t base = ((size_t)(mt * 256 + kt0 + ks) * 64 + lane) * 4;
        V16 ah, al;
        ah.u = *(const uint4*)(Gt1h + base);
        al.u = *(const uint4*)(Gt1l + base);
#pragma unroll
        for (int nt = 0; nt < 4; ++nt) {
            unsigned int by8 = (bw[(nt * 16 + n) * 36 + ks] >> (quad * 8)) & 0xFFu;
            V16 bf;
            bf.u = make_uint4(bits2bf(by8), bits2bf(by8 >> 2),
                              bits2bf(by8 >> 4), bits2bf(by8 >> 6));
            acc[nt] = __builtin_amdgcn_mfma_f32_16x16x32_bf16(ah.s, bf.s, acc[nt], 0, 0, 0);
            acc[nt] = __builtin_amdgcn_mfma_f32_16x16x32_bf16(al.s, bf.s, acc[nt], 0, 0, 0);
        }
    }
    const int s = blockIdx.y;
#pragma unroll
    for (int nt = 0; nt < 4; ++nt) {
        const int node = node0 + nt * 16 + n;
        *(f32x4*)&num1p[((size_t)s * NN + node) * 64 + mt * 16 + quad * 4] = acc[nt];
    }
}

// ---------------------------------------------------------------------------
// K4: layer-1 epilogue + layer-2 prep. 1024 blocks x 256 (8 nodes/block,
// 2 per wave). float4 LDS broadcasts for z/o. Writes Gt2 tiled (M=48);
// block = one quad of a 32-node kt tile.
// ---------------------------------------------------------------------------
__global__ __launch_bounds__(256) void k_ep1(const float* __restrict__ num1p,
                                             const float* __restrict__ den1,
                                             const float* __restrict__ W21,
                                             const float* __restrict__ b21,
                                             const float* __restrict__ Wg2,
                                             const float* __restrict__ a2,
                                             unsigned int* __restrict__ Gt2h,
                                             unsigned int* __restrict__ Gt2l) {
    __shared__ float w21sh[64 * 64];
    __shared__ float wg2sh[64 * 32];
    __shared__ float zsh[4][64];
    __shared__ float osh[4][64];
    __shared__ unsigned int g2sh[32][9];
    __shared__ unsigned int u2sh[8];
    const int tid = threadIdx.x, wv = tid >> 6, lane = tid & 63;
    const int node0 = blockIdx.x * 8;
    {
        const float4* s4 = (const float4*)W21;
        float4* d4 = (float4*)w21sh;
        d4[tid] = s4[tid];
        d4[tid + 256] = s4[tid + 256];
        d4[tid + 512] = s4[tid + 512];
        d4[tid + 768] = s4[tid + 768];
        ((float4*)wg2sh)[tid] = ((const float4*)Wg2)[tid];
        ((float4*)wg2sh)[tid + 256] = ((const float4*)Wg2)[tid + 256];
    }
    const float bb = b21[lane];
    const int l32 = lane & 31;
    const float a2v = (lane < 32) ? a2[32 + l32] : 0.f;
    __syncthreads();
    for (int it = 0; it < 2; ++it) {
        const int node = node0 + wv * 2 + it;
        float sacc = 0.f;
#pragma unroll
        for (int sp = 0; sp < 8; ++sp)
            sacc += num1p[((size_t)sp * NN + node) * 64 + lane];
        zsh[wv][lane] = sacc / den1[node];
        __builtin_amdgcn_wave_barrier();
        const float4* zv = (const float4*)&zsh[wv][0];
        float o0 = 0.f, o1 = 0.f;
#pragma unroll 4
        for (int c4 = 0; c4 < 16; ++c4) {
            float4 z4 = zv[c4];
            const int c = c4 * 4;
            o0 += z4.x * w21sh[(c + 0) * 64 + lane] + z4.y * w21sh[(c + 1) * 64 + lane];
            o1 += z4.z * w21sh[(c + 2) * 64 + lane] + z4.w * w21sh[(c + 3) * 64 + lane];
        }
        float o = elu_f(bb + o0 + o1);
        osh[wv][lane] = o;
        __builtin_amdgcn_wave_barrier();
        const float4* ov = (const float4*)&osh[wv][0];
        float h0 = 0.f, h1 = 0.f;
#pragma unroll 4
        for (int c4 = 0; c4 < 16; ++c4) {
            float4 o4 = ov[c4];
            const int c = c4 * 4;
            h0 += o4.x * wg2sh[(c + 0) * 32 + l32] + o4.y * wg2sh[(c + 1) * 32 + l32];
            h1 += o4.z * wg2sh[(c + 2) * 32 + l32] + o4.w * wg2sh[(c + 3) * 32 + l32];
        }
        float hval = h0 + h1;
        float pp = hval * a2v;
#pragma unroll
        for (int off = 32; off; off >>= 1) pp += __shfl_down(pp, off);
        float d2 = __shfl(pp, 0);
        float uu = expf(d2);
        const int nodeloc = wv * 2 + it;
        if (lane == 0) u2sh[nodeloc] = split_pack(uu);
        if (lane < 32) g2sh[l32][nodeloc] = split_pack(uu * hval);
    }
    __syncthreads();
    if (tid < 48) {   // Gt2 writer: 3 mt x 16 ml; block = quad (bx&3) of tile kt
        const int mt = tid >> 4, ml = tid & 15;
        const int quad_w = blockIdx.x & 3, kt = blockIdx.x >> 2;
        const int lane2 = quad_w * 16 + ml;
        uint4 hv, lv;
        unsigned int g0, g1;
#define PACK_Q(Q, F)                                                   \
        {                                                              \
            int j0 = 2 * Q;                                            \
            if (mt < 2) { g0 = g2sh[mt * 16 + ml][j0];                 \
                          g1 = g2sh[mt * 16 + ml][j0 + 1]; }           \
            else if (ml == 0) { g0 = u2sh[j0]; g1 = u2sh[j0 + 1]; }    \
            else { g0 = 0; g1 = 0; }                                   \
            hv.F = (g0 >> 16) | (g1 & 0xFFFF0000u);                    \
            lv.F = (g0 & 0xFFFFu) | (g1 << 16);                        \
        }
        PACK_Q(0, x) PACK_Q(1, y) PACK_Q(2, z) PACK_Q(3, w)
#undef PACK_Q
        size_t base = ((size_t)(mt * 256 + kt) * 64 + lane2) * 4;
        *(uint4*)(Gt2h + base) = hv;
        *(uint4*)(Gt2l + base) = lv;
    }
}

// ---------------------------------------------------------------------------
// K5: layer-2 MFMA, M=48. Wave = m-tile (wave 3 idles after staging).
// grid (128, 8).
// ---------------------------------------------------------------------------
__global__ __launch_bounds__(256) void k_attn2(const unsigned int* __restrict__ Wb32,
                                               const unsigned int* __restrict__ Gt2h,
                                               const unsigned int* __restrict__ Gt2l,
                                               float* __restrict__ num2p) {
    __shared__ unsigned int bw[64 * 36];
    const int tid = threadIdx.x, wv = tid >> 6, lane = tid & 63;
    const int node0 = blockIdx.x * 64;
    const int kt0 = blockIdx.y * 32;
    {
        const int r = tid >> 2, part = tid & 3;
        const uint4* src = (const uint4*)(Wb32 + (size_t)(node0 + r) * 256 + kt0 + part * 8);
        uint4 v0 = src[0], v1 = src[1];
        *(uint4*)&bw[r * 36 + part * 8] = v0;
        *(uint4*)&bw[r * 36 + part * 8 + 4] = v1;
    }
    __syncthreads();
    if (wv == 3) return;
    const int n = lane & 15, quad = lane >> 4;
    const int mt = wv;
    f32x4 acc[4];
#pragma unroll
    for (int nt = 0; nt < 4; ++nt) acc[nt] = (f32x4){0.f, 0.f, 0.f, 0.f};
#pragma unroll 4
    for (int ks = 0; ks < 32; ++ks) {
        size_t base = ((size_t)(mt * 256 + kt0 + ks) * 64 + lane) * 4;
        V16 ah, al;
        ah.u = *(const uint4*)(Gt2h + base);
        al.u = *(const uint4*)(Gt2l + base);
#pragma unroll
        for (int nt = 0; nt < 4; ++nt) {
            unsigned int by8 = (bw[(nt * 16 + n) * 36 + ks] >> (quad * 8)) & 0xFFu;
            V16 bf;
            bf.u = make_uint4(bits2bf(by8), bits2bf(by8 >> 2),
                              bits2bf(by8 >> 4), bits2bf(by8 >> 6));
            acc[nt] = __builtin_amdgcn_mfma_f32_16x16x32_bf16(ah.s, bf.s, acc[nt], 0, 0, 0);
            acc[nt] = __builtin_amdgcn_mfma_f32_16x16x32_bf16(al.s, bf.s, acc[nt], 0, 0, 0);
        }
    }
    const int s = blockIdx.y;
#pragma unroll
    for (int nt = 0; nt < 4; ++nt) {
        const int node = node0 + nt * 16 + n;
        *(f32x4*)&num2p[((size_t)s * NN + node) * 48 + mt * 16 + quad * 4] = acc[nt];
    }
}

// ---------------------------------------------------------------------------
// K6: layer-2 epilogue + column partials. 256 blocks x 512 (32 rows/block,
// 4 per wave). gpart[256][64].
// ---------------------------------------------------------------------------
__global__ __launch_bounds__(512) void k_ep2(const float* __restrict__ num2p,
                                             const float* __restrict__ W22,
                                             const float* __restrict__ b22,
                                             float* __restrict__ gpart) {
    __shared__ float w22sh[32 * 64];
    __shared__ float zsh[8][32];
    __shared__ float gsh[8][64];
    const int tid = threadIdx.x, wv = tid >> 6, lane = tid & 63;
    ((float4*)w22sh)[tid] = ((const float4*)W22)[tid];
    const float bb = b22[lane];
    __syncthreads();
    float greg = 0.f;
    for (int it = 0; it < 4; ++it) {
        const int row = blockIdx.x * 32 + wv * 4 + it;
        float val = 0.f;
        if (lane < 33) {
#pragma unroll
            for (int sp = 0; sp < 8; ++sp)
                val += num2p[((size_t)sp * NN + row) * 48 + lane];
        }
        float den = __shfl(val, 32);
        if (lane < 32) zsh[wv][lane] = val / den;
        __builtin_amdgcn_wave_barrier();
        const float4* zv = (const float4*)&zsh[wv][0];
        float o0 = 0.f, o1 = 0.f;
#pragma unroll 4
        for (int c4 = 0; c4 < 8; ++c4) {
            float4 z4 = zv[c4];
            const int c = c4 * 4;
            o0 += z4.x * w22sh[(c + 0) * 64 + lane] + z4.y * w22sh[(c + 1) * 64 + lane];
            o1 += z4.z * w22sh[(c + 2) * 64 + lane] + z4.w * w22sh[(c + 3) * 64 + lane];
        }
        greg += elu_f(bb + o0 + o1);
        __builtin_amdgcn_wave_barrier();
    }
    gsh[wv][lane] = greg;
    __syncthreads();
    if (tid < 64) {
        float s = 0.f;
#pragma unroll
        for (int w = 0; w < 8; ++w) s += gsh[w][tid];
        gpart[(size_t)blockIdx.x * 64 + tid] = s;
    }
}

// ---------------------------------------------------------------------------
// K7: mean + MLP head. gpart is 256 rows (64 KB).
// ---------------------------------------------------------------------------
__global__ __launch_bounds__(256) void k_head(const float* __restrict__ gpart,
                                              const float* __restrict__ M1,
                                              const float* __restrict__ bm1,
                                              const float* __restrict__ M2,
                                              const float* __restrict__ bm2,
                                              float* __restrict__ outp) {
    __shared__ float part[4][64];
    __shared__ float gsh[64];
    __shared__ float hsh[64];
    const int tid = threadIdx.x, col = tid & 63, p = tid >> 6;
    float s = 0.f;
    for (int b = p * 64; b < p * 64 + 64; ++b)
        s += gpart[(size_t)b * 64 + col];
    part[p][col] = s;
    __syncthreads();
    if (tid < 64)
        gsh[tid] = (part[0][tid] + part[1][tid] + part[2][tid] + part[3][tid])
                   * (1.0f / 8192.0f);
    __syncthreads();
    if (tid < 64) {
        float h = bm1[tid];
        for (int c = 0; c < 64; ++c) h += gsh[c] * M1[c * 64 + tid];
        hsh[tid] = h > 0.f ? h : 0.f;
    }
    __syncthreads();
    if (tid < 2) {
        float o = bm2[tid];
        for (int j = 0; j < 64; ++j) o += hsh[j] * M2[j * 2 + tid];
        outp[tid] = o;
    }
}

// ---------------------------------------------------------------------------
extern "C" void kernel_launch(void* const* d_in, const int* in_sizes, int n_in,
                              void* d_out, int out_size, void* d_ws, size_t ws_size,
                              hipStream_t stream) {
    const float* X   = (const float*)d_in[0];
    const int*   A   = (const int*)  d_in[1];
    const float* W1  = (const float*)d_in[2];
    const float* a1  = (const float*)d_in[3];
    const float* W21 = (const float*)d_in[4];
    const float* b21 = (const float*)d_in[5];
    const float* Wg2 = (const float*)d_in[6];
    const float* a2  = (const float*)d_in[7];
    const float* W22 = (const float*)d_in[8];
    const float* b22 = (const float*)d_in[9];
    const float* M1  = (const float*)d_in[10];
    const float* bm1 = (const float*)d_in[11];
    const float* M2  = (const float*)d_in[12];
    const float* bm2 = (const float*)d_in[13];
    float* out = (float*)d_out;

    char* ws = (char*)d_ws;
    unsigned int* Wbits = (unsigned int*)(ws + OFF_WBITS);
    unsigned int* Gt1h  = (unsigned int*)(ws + OFF_GT1H);
    unsigned int* Gt1l  = (unsigned int*)(ws + OFF_GT1L);
    unsigned int* Gt2h  = (unsigned int*)(ws + OFF_GT2H);
    unsigned int* Gt2l  = (unsigned int*)(ws + OFF_GT2L);
    float* Dp    = (float*)(ws + OFF_DP);
    float* u1    = (float*)(ws + OFF_U1);
    float* den1  = (float*)(ws + OFF_DEN1);
    float* gpart = (float*)(ws + OFF_GPART);
    float* nump  = (float*)(ws + OFF_NUMP);

    k_xw1m <<<dim3(128, 4), 256, 0, stream>>>(X, W1, Dp);
    k_xcomb<<<256, 256, 0, stream>>>(Dp, a1, Gt1h, Gt1l, u1);
    k_pack <<<2048, 256, 0, stream>>>(A, u1, Wbits, den1);
    k_attn1<<<dim3(128, 8), 256, 0, stream>>>(Wbits, Gt1h, Gt1l, nump);
    k_ep1  <<<1024, 256, 0, stream>>>(nump, den1, W21, b21, Wg2, a2, Gt2h, Gt2l);
    k_attn2<<<dim3(128, 8), 256, 0, stream>>>(Wbits, Gt2h, Gt2l, nump);
    k_ep2  <<<256, 512, 0, stream>>>(nump, W22, b22, gpart);
    k_head <<<1, 256, 0, stream>>>(gpart, M1, bm1, M2, bm2, out);
}

// Round 7
// 507.283 us; speedup vs baseline: 1.0240x; 1.0240x over previous
//
#include <hip/hip_runtime.h>

// ============================================================================
// GAT classifier, N=8192. Softmax cancels the source term:
//   Z = (A @ (u*H)) / (A @ u),  u = exp(H @ a_dst).
// Round 7: structural fusion.
//  - k_attn1f: pack A-tile (HBM, read once) -> LDS bits + Wbits slice, then
//    layer-1 MFMA from LDS. A-stream overlaps MFMA; k_pack dispatch removed.
//  - den1 rides the MFMA as m-tile 4 of M=80 (u1 in feature row 64), same
//    trick layer 2 already uses (M=48). No u1 global, no den machinery.
// ============================================================================

#define NN 8192

typedef __attribute__((ext_vector_type(8))) short s16x8;   // 8 bf16 (4 VGPR)
typedef __attribute__((ext_vector_type(4))) float f32x4;   // MFMA C/D
union V16 { uint4 u; s16x8 s; };

// ---- workspace layout ----
static constexpr size_t OFF_WBITS = 0;                                  // 8 MB bitmask
static constexpr size_t OFF_GT1H  = (size_t)8 << 20;                    // 1.25 MB Gt1 hi (tiled, M=80)
static constexpr size_t OFF_GT1L  = ((size_t)9 << 20) + 512 * 1024;     // 1.25 MB Gt1 lo
static constexpr size_t OFF_GT2H  = (size_t)11 << 20;                   // 768 KB Gt2 hi (tiled, M=48)
static constexpr size_t OFF_GT2L  = (size_t)12 << 20;                   // 768 KB Gt2 lo
static constexpr size_t OFF_GPART = (size_t)13 << 20;                   // 64 KB
static constexpr size_t OFF_NUMP  = (size_t)16 << 20;                   // 20 MB num1p (stride 80); num2p reuses
static constexpr size_t OFF_DP    = (size_t)40 << 20;                   // 8 MB xw1 partials

__device__ __forceinline__ float elu_f(float x) {
    return x > 0.f ? x : expm1f(x);
}
__device__ __forceinline__ unsigned int bf16_rne(float x) {
    unsigned int u = __float_as_uint(x);
    return (u + 0x7FFFu + ((u >> 16) & 1u)) >> 16;
}
// pack (hi<<16)|lo where x ~= bf16(hi) + bf16(lo)
__device__ __forceinline__ unsigned int split_pack(float g) {
    unsigned int hi = bf16_rne(g);
    float fhi = __uint_as_float(hi << 16);
    unsigned int lo = bf16_rne(g - fhi);
    return (hi << 16) | lo;
}
__device__ __forceinline__ void split3(float f, unsigned int& h, unsigned int& m,
                                       unsigned int& l) {
    h = bf16_rne(f);
    float fh = __uint_as_float(h << 16);
    float r1 = f - fh;
    m = bf16_rne(r1);
    float fm = __uint_as_float(m << 16);
    l = bf16_rne(r1 - fm);
}
// 2 adjacency bits -> uint of 2 packed bf16 {0,1}
__device__ __forceinline__ unsigned int bits2bf(unsigned int b2) {
    return (b2 & 1u) * 0x3F80u + (b2 & 2u) * 0x1FC00000u;
}

// ---------------------------------------------------------------------------
// K1: H1 = X @ W1 on MFMA. W1^T fragments built in LDS per block. grid
// (128 node-groups of 64, 4 ksplits of 192 k). Wave = n-tile. B = X rows
// split 3-way bf16; 5 MFMA terms.
// ---------------------------------------------------------------------------
__global__ __launch_bounds__(256) void k_xw1m(const float* __restrict__ X,
                                              const float* __restrict__ W1,
                                              float* __restrict__ Dp) {
    __shared__ unsigned int fh[6144];   // 24 KB: 4mt x 6kt x 64 lanes x uint4
    __shared__ unsigned int fl[6144];   // 24 KB
    const int tid = threadIdx.x, wv = tid >> 6, lane = tid & 63;
    const int ks = blockIdx.y;
    for (int i = tid; i < 6144; i += 256) {
        const int feat = i & 63, kp = i >> 6;       // kp 0..95 (k-pairs)
        const int kg = ks * 192 + 2 * kp;
        float w0 = W1[(size_t)kg * 64 + feat];
        float w1 = W1[(size_t)(kg + 1) * 64 + feat];
        unsigned int h0 = bf16_rne(w0);
        unsigned int l0 = bf16_rne(w0 - __uint_as_float(h0 << 16));
        unsigned int h1 = bf16_rne(w1);
        unsigned int l1 = bf16_rne(w1 - __uint_as_float(h1 << 16));
        const int mt = feat >> 4, n = feat & 15;
        const int ktl = kp >> 4, rem = kp & 15, quad = rem >> 2, q = rem & 3;
        const int idx = ((mt * 6 + ktl) * 64 + quad * 16 + n) * 4 + q;
        fh[idx] = h0 | (h1 << 16);
        fl[idx] = l0 | (l1 << 16);
    }
    __syncthreads();
    const int n = lane & 15, quad = lane >> 4;
    const int node = blockIdx.x * 64 + wv * 16 + n;
    const int ntg = blockIdx.x * 4 + wv;
    f32x4 acc[4];
#pragma unroll
    for (int mt = 0; mt < 4; ++mt) acc[mt] = (f32x4){0.f, 0.f, 0.f, 0.f};
    const float4* X4 = (const float4*)X;
    for (int kk = 0; kk < 6; ++kk) {
        const int ktg = ks * 6 + kk;
        float4 x01 = X4[(size_t)node * 192 + ktg * 8 + quad * 2];
        float4 x23 = X4[(size_t)node * 192 + ktg * 8 + quad * 2 + 1];
        float xf[8] = {x01.x, x01.y, x01.z, x01.w, x23.x, x23.y, x23.z, x23.w};
        V16 bh, bm, bl;
        unsigned int* bhp = (unsigned int*)&bh.u;
        unsigned int* bmp = (unsigned int*)&bm.u;
        unsigned int* blp = (unsigned int*)&bl.u;
#pragma unroll
        for (int q = 0; q < 4; ++q) {
            unsigned int h0, m0, l0, h1, m1, l1;
            split3(xf[2 * q], h0, m0, l0);
            split3(xf[2 * q + 1], h1, m1, l1);
            bhp[q] = h0 | (h1 << 16);
            bmp[q] = m0 | (m1 << 16);
            blp[q] = l0 | (l1 << 16);
        }
#pragma unroll
        for (int mt = 0; mt < 4; ++mt) {
            const int base = ((mt * 6 + kk) * 64 + lane) * 4;
            V16 awh, awl;
            awh.u = *(const uint4*)&fh[base];
            awl.u = *(const uint4*)&fl[base];
            acc[mt] = __builtin_amdgcn_mfma_f32_16x16x32_bf16(awh.s, bh.s, acc[mt], 0, 0, 0);
            acc[mt] = __builtin_amdgcn_mfma_f32_16x16x32_bf16(awh.s, bm.s, acc[mt], 0, 0, 0);
            acc[mt] = __builtin_amdgcn_mfma_f32_16x16x32_bf16(awh.s, bl.s, acc[mt], 0, 0, 0);
            acc[mt] = __builtin_amdgcn_mfma_f32_16x16x32_bf16(awl.s, bh.s, acc[mt], 0, 0, 0);
            acc[mt] = __builtin_amdgcn_mfma_f32_16x16x32_bf16(awl.s, bm.s, acc[mt], 0, 0, 0);
        }
    }
#pragma unroll
    for (int mt = 0; mt < 4; ++mt)
        *(f32x4*)&Dp[(size_t)(((ks * 4 + mt) * 512 + ntg) * 64 + lane) * 4] = acc[mt];
}

// ---------------------------------------------------------------------------
// K1b: reduce Dp ksplits -> H1; u1 = exp(H1 @ a1[64:]); write Gt1 tiled
// with M=80: mt 0-3 = features, mt 4 = [u1; zeros] (den1 rides the MFMA).
// ---------------------------------------------------------------------------
__global__ __launch_bounds__(256) void k_xcomb(const float* __restrict__ Dp,
                                               const float* __restrict__ a1,
                                               unsigned int* __restrict__ Gt1h,
                                               unsigned int* __restrict__ Gt1l) {
    __shared__ float Hsh[64][33];
    __shared__ float us[32];
    const int tid = threadIdx.x;
    if (tid < 128) {
        const int ntl = tid >> 6, lane = tid & 63;
        const int n = lane & 15, quad = lane >> 4;
        const int ntg = blockIdx.x * 2 + ntl;
        float dpart = 0.f;
#pragma unroll
        for (int mt = 0; mt < 4; ++mt) {
            float v[4] = {0.f, 0.f, 0.f, 0.f};
#pragma unroll
            for (int ksp = 0; ksp < 4; ++ksp) {
                const float* p = &Dp[(size_t)(((ksp * 4 + mt) * 512 + ntg) * 64 + lane) * 4];
                v[0] += p[0]; v[1] += p[1]; v[2] += p[2]; v[3] += p[3];
            }
#pragma unroll
            for (int r = 0; r < 4; ++r) {
                int feat = mt * 16 + quad * 4 + r;
                Hsh[feat][ntl * 16 + n] = v[r];
                dpart += v[r] * a1[64 + feat];
            }
        }
        dpart += __shfl_xor(dpart, 16);
        dpart += __shfl_xor(dpart, 32);
        float uu = expf(dpart);
        if (lane < 16) us[ntl * 16 + lane] = uu;
    }
    __syncthreads();
    {   // feature tiles mt 0-3
        const int mt = tid >> 6, lane = tid & 63;
        const int feat = mt * 16 + (lane & 15), quad = lane >> 4;
        uint4 hv, lv;
        unsigned int g0, g1;
#define PACK_Q(Q, FX)                                                   \
        {                                                               \
            int j0 = quad * 8 + 2 * Q;                                  \
            g0 = split_pack(us[j0] * Hsh[feat][j0]);                    \
            g1 = split_pack(us[j0 + 1] * Hsh[feat][j0 + 1]);            \
            hv.FX = (g0 >> 16) | (g1 & 0xFFFF0000u);                    \
            lv.FX = (g0 & 0xFFFFu) | (g1 << 16);                        \
        }
        PACK_Q(0, x) PACK_Q(1, y) PACK_Q(2, z) PACK_Q(3, w)
#undef PACK_Q
        size_t base = ((size_t)(mt * 256 + blockIdx.x) * 64 + lane) * 4;
        *(uint4*)(Gt1h + base) = hv;
        *(uint4*)(Gt1l + base) = lv;
    }
    if (tid < 64) {   // u-tile mt 4: feature row 0 = u1, rows 1-15 = 0
        const int ml = tid & 15, quad = tid >> 4;
        uint4 hv, lv;
        unsigned int g0, g1;
#define PACK_Q(Q, FX)                                                   \
        {                                                               \
            int j0 = quad * 8 + 2 * Q;                                  \
            if (ml == 0) { g0 = split_pack(us[j0]);                     \
                           g1 = split_pack(us[j0 + 1]); }               \
            else { g0 = 0; g1 = 0; }                                    \
            hv.FX = (g0 >> 16) | (g1 & 0xFFFF0000u);                    \
            lv.FX = (g0 & 0xFFFFu) | (g1 << 16);                        \
        }
        PACK_Q(0, x) PACK_Q(1, y) PACK_Q(2, z) PACK_Q(3, w)
#undef PACK_Q
        size_t base = ((size_t)(4 * 256 + blockIdx.x) * 64 + tid) * 4;
        *(uint4*)(Gt1h + base) = hv;
        *(uint4*)(Gt1l + base) = lv;
    }
}

// ---------------------------------------------------------------------------
// K2: FUSED pack + layer-1 MFMA. grid (128 node-groups, 8 k-chunks of 1024),
// block = 320 (5 waves). Phase 1 (waves 0-3): stream this block's A-tile
// (HBM, once globally), build 16-bit masks -> LDS (padded ushort rows).
// Phase 2: write Wbits slice for attn2; 5 waves MFMA (wave = m-tile, mt 4 =
// u-tile -> den1 partial in num1p col 64). num1p stride 80.
// ---------------------------------------------------------------------------
__global__ __launch_bounds__(320) void k_attn1f(const int* __restrict__ A,
                                                const unsigned int* __restrict__ Gt1h,
                                                const unsigned int* __restrict__ Gt1l,
                                                unsigned int* __restrict__ Wb32,
                                                float* __restrict__ num1p) {
    __shared__ unsigned int bw[64 * 33];    // ushort view: [64][66] (pad 2)
    const int tid = threadIdx.x, wv = tid >> 6, lane = tid & 63;
    const int node0 = blockIdx.x * 64;
    const int kc = blockIdx.y;              // k-chunk: cols kc*1024..+1024
    if (wv < 4) {
        unsigned short* msh = (unsigned short*)bw;
        for (int rr = 0; rr < 16; ++rr) {
            const int r = wv * 16 + rr;
            const int4* A4 = (const int4*)(A + (size_t)(node0 + r) * NN + kc * 1024 + lane * 16);
            int4 a0 = A4[0], a1 = A4[1], a2 = A4[2], a3 = A4[3];
            unsigned int m0 = 0;
            m0 |= ((a0.x != 0) << 0)  | ((a0.y != 0) << 1)  |
                  ((a0.z != 0) << 2)  | ((a0.w != 0) << 3);
            m0 |= ((a1.x != 0) << 4)  | ((a1.y != 0) << 5)  |
                  ((a1.z != 0) << 6)  | ((a1.w != 0) << 7);
            m0 |= ((a2.x != 0) << 8)  | ((a2.y != 0) << 9)  |
                  ((a2.z != 0) << 10) | ((a2.w != 0) << 11);
            m0 |= ((a3.x != 0) << 12) | ((a3.y != 0) << 13) |
                  ((a3.z != 0) << 14) | ((a3.w != 0) << 15);
            msh[r * 66 + lane] = (unsigned short)m0;
        }
    }
    __syncthreads();
    // Wbits slice for attn2 (threads 0-255): 8 scalar LDS reads -> 2 uint4 stores
    if (tid < 256) {
        const int r = tid >> 2, part = tid & 3;
        uint4 v0, v1;
        v0.x = bw[r * 33 + part * 8 + 0]; v0.y = bw[r * 33 + part * 8 + 1];
        v0.z = bw[r * 33 + part * 8 + 2]; v0.w = bw[r * 33 + part * 8 + 3];
        v1.x = bw[r * 33 + part * 8 + 4]; v1.y = bw[r * 33 + part * 8 + 5];
        v1.z = bw[r * 33 + part * 8 + 6]; v1.w = bw[r * 33 + part * 8 + 7];
        uint4* dst = (uint4*)(Wb32 + (size_t)(node0 + r) * 256 + kc * 32 + part * 8);
        dst[0] = v0; dst[1] = v1;
    }
    // MFMA: wave = m-tile (0-3 features, 4 = u-tile/den)
    const int n = lane & 15, quad = lane >> 4;
    const int mt = wv;
    const int kt0 = kc * 32;
    f32x4 acc[4];
#pragma unroll
    for (int nt = 0; nt < 4; ++nt) acc[nt] = (f32x4){0.f, 0.f, 0.f, 0.f};
#pragma unroll 4
    for (int ks = 0; ks < 32; ++ks) {
        size_t base = ((size_t)(mt * 256 + kt0 + ks) * 64 + lane) * 4;
        V16 ah, al;
        ah.u = *(const uint4*)(Gt1h + base);
        al.u = *(const uint4*)(Gt1l + base);
#pragma unroll
        for (int nt = 0; nt < 4; ++nt) {
            unsigned int by8 = (bw[(nt * 16 + n) * 33 + ks] >> (quad * 8)) & 0xFFu;
            V16 bf;
            bf.u = make_uint4(bits2bf(by8), bits2bf(by8 >> 2),
                              bits2bf(by8 >> 4), bits2bf(by8 >> 6));
            acc[nt] = __builtin_amdgcn_mfma_f32_16x16x32_bf16(ah.s, bf.s, acc[nt], 0, 0, 0);
            acc[nt] = __builtin_amdgcn_mfma_f32_16x16x32_bf16(al.s, bf.s, acc[nt], 0, 0, 0);
        }
    }
    const int s = blockIdx.y;
#pragma unroll
    for (int nt = 0; nt < 4; ++nt) {
        const int node = node0 + nt * 16 + n;
        *(f32x4*)&num1p[((size_t)s * NN + node) * 80 + mt * 16 + quad * 4] = acc[nt];
    }
}

// ---------------------------------------------------------------------------
// K4: layer-1 epilogue + layer-2 prep. 1024 blocks x 256 (8 nodes/block,
// 2 per wave). den1 = sum of num1p col 64. Writes Gt2 tiled (M=48);
// block = one quad of a 32-node kt tile.
// ---------------------------------------------------------------------------
__global__ __launch_bounds__(256) void k_ep1(const float* __restrict__ num1p,
                                             const float* __restrict__ W21,
                                             const float* __restrict__ b21,
                                             const float* __restrict__ Wg2,
                                             const float* __restrict__ a2,
                                             unsigned int* __restrict__ Gt2h,
                                             unsigned int* __restrict__ Gt2l) {
    __shared__ float w21sh[64 * 64];
    __shared__ float wg2sh[64 * 32];
    __shared__ float zsh[4][64];
    __shared__ float osh[4][64];
    __shared__ unsigned int g2sh[32][9];
    __shared__ unsigned int u2sh[8];
    const int tid = threadIdx.x, wv = tid >> 6, lane = tid & 63;
    const int node0 = blockIdx.x * 8;
    {
        const float4* s4 = (const float4*)W21;
        float4* d4 = (float4*)w21sh;
        d4[tid] = s4[tid];
        d4[tid + 256] = s4[tid + 256];
        d4[tid + 512] = s4[tid + 512];
        d4[tid + 768] = s4[tid + 768];
        ((float4*)wg2sh)[tid] = ((const float4*)Wg2)[tid];
        ((float4*)wg2sh)[tid + 256] = ((const float4*)Wg2)[tid + 256];
    }
    const float bb = b21[lane];
    const int l32 = lane & 31;
    const float a2v = (lane < 32) ? a2[32 + l32] : 0.f;
    __syncthreads();
    for (int it = 0; it < 2; ++it) {
        const int node = node0 + wv * 2 + it;
        float sacc = 0.f, dnum = 0.f;
#pragma unroll
        for (int sp = 0; sp < 8; ++sp) {
            const float* base = &num1p[((size_t)sp * NN + node) * 80];
            sacc += base[lane];
            dnum += base[64];
        }
        zsh[wv][lane] = sacc / dnum;
        __builtin_amdgcn_wave_barrier();
        const float4* zv = (const float4*)&zsh[wv][0];
        float o0 = 0.f, o1 = 0.f;
#pragma unroll 4
        for (int c4 = 0; c4 < 16; ++c4) {
            float4 z4 = zv[c4];
            const int c = c4 * 4;
            o0 += z4.x * w21sh[(c + 0) * 64 + lane] + z4.y * w21sh[(c + 1) * 64 + lane];
            o1 += z4.z * w21sh[(c + 2) * 64 + lane] + z4.w * w21sh[(c + 3) * 64 + lane];
        }
        float o = elu_f(bb + o0 + o1);
        osh[wv][lane] = o;
        __builtin_amdgcn_wave_barrier();
        const float4* ov = (const float4*)&osh[wv][0];
        float h0 = 0.f, h1 = 0.f;
#pragma unroll 4
        for (int c4 = 0; c4 < 16; ++c4) {
            float4 o4 = ov[c4];
            const int c = c4 * 4;
            h0 += o4.x * wg2sh[(c + 0) * 32 + l32] + o4.y * wg2sh[(c + 1) * 32 + l32];
            h1 += o4.z * wg2sh[(c + 2) * 32 + l32] + o4.w * wg2sh[(c + 3) * 32 + l32];
        }
        float hval = h0 + h1;
        float pp = hval * a2v;
#pragma unroll
        for (int off = 32; off; off >>= 1) pp += __shfl_down(pp, off);
        float d2 = __shfl(pp, 0);
        float uu = expf(d2);
        const int nodeloc = wv * 2 + it;
        if (lane == 0) u2sh[nodeloc] = split_pack(uu);
        if (lane < 32) g2sh[l32][nodeloc] = split_pack(uu * hval);
    }
    __syncthreads();
    if (tid < 48) {   // Gt2 writer: 3 mt x 16 ml; block = quad (bx&3) of tile kt
        const int mt = tid >> 4, ml = tid & 15;
        const int quad_w = blockIdx.x & 3, kt = blockIdx.x >> 2;
        const int lane2 = quad_w * 16 + ml;
        uint4 hv, lv;
        unsigned int g0, g1;
#define PACK_Q(Q, F)                                                   \
        {                                                              \
            int j0 = 2 * Q;                                            \
            if (mt < 2) { g0 = g2sh[mt * 16 + ml][j0];                 \
                          g1 = g2sh[mt * 16 + ml][j0 + 1]; }           \
            else if (ml == 0) { g0 = u2sh[j0]; g1 = u2sh[j0 + 1]; }    \
            else { g0 = 0; g1 = 0; }                                   \
            hv.F = (g0 >> 16) | (g1 & 0xFFFF0000u);                    \
            lv.F = (g0 & 0xFFFFu) | (g1 << 16);                        \
        }
        PACK_Q(0, x) PACK_Q(1, y) PACK_Q(2, z) PACK_Q(3, w)
#undef PACK_Q
        size_t base = ((size_t)(mt * 256 + kt) * 64 + lane2) * 4;
        *(uint4*)(Gt2h + base) = hv;
        *(uint4*)(Gt2l + base) = lv;
    }
}

// ---------------------------------------------------------------------------
// K5: layer-2 MFMA, M=48. Wave = m-tile (wave 3 idles after staging).
// grid (128, 8). Bits from Wbits (written by k_attn1f).
// ---------------------------------------------------------------------------
__global__ __launch_bounds__(256) void k_attn2(const unsigned int* __restrict__ Wb32,
                                               const unsigned int* __restrict__ Gt2h,
                                               const unsigned int* __restrict__ Gt2l,
                                               float* __restrict__ num2p) {
    __shared__ unsigned int bw[64 * 36];
    const int tid = threadIdx.x, wv = tid >> 6, lane = tid & 63;
    const int node0 = blockIdx.x * 64;
    const int kt0 = blockIdx.y * 32;
    {
        const int r = tid >> 2, part = tid & 3;
        const uint4* src = (const uint4*)(Wb32 + (size_t)(node0 + r) * 256 + kt0 + part * 8);
        uint4 v0 = src[0], v1 = src[1];
        *(uint4*)&bw[r * 36 + part * 8] = v0;
        *(uint4*)&bw[r * 36 + part * 8 + 4] = v1;
    }
    __syncthreads();
    if (wv == 3) return;
    const int n = lane & 15, quad = lane >> 4;
    const int mt = wv;
    f32x4 acc[4];
#pragma unroll
    for (int nt = 0; nt < 4; ++nt) acc[nt] = (f32x4){0.f, 0.f, 0.f, 0.f};
#pragma unroll 4
    for (int ks = 0; ks < 32; ++ks) {
        size_t base = ((size_t)(mt * 256 + kt0 + ks) * 64 + lane) * 4;
        V16 ah, al;
        ah.u = *(const uint4*)(Gt2h + base);
        al.u = *(const uint4*)(Gt2l + base);
#pragma unroll
        for (int nt = 0; nt < 4; ++nt) {
            unsigned int by8 = (bw[(nt * 16 + n) * 36 + ks] >> (quad * 8)) & 0xFFu;
            V16 bf;
            bf.u = make_uint4(bits2bf(by8), bits2bf(by8 >> 2),
                              bits2bf(by8 >> 4), bits2bf(by8 >> 6));
            acc[nt] = __builtin_amdgcn_mfma_f32_16x16x32_bf16(ah.s, bf.s, acc[nt], 0, 0, 0);
            acc[nt] = __builtin_amdgcn_mfma_f32_16x16x32_bf16(al.s, bf.s, acc[nt], 0, 0, 0);
        }
    }
    const int s = blockIdx.y;
#pragma unroll
    for (int nt = 0; nt < 4; ++nt) {
        const int node = node0 + nt * 16 + n;
        *(f32x4*)&num2p[((size_t)s * NN + node) * 48 + mt * 16 + quad * 4] = acc[nt];
    }
}

// ---------------------------------------------------------------------------
// K6: layer-2 epilogue + column partials. 256 blocks x 512 (32 rows/block,
// 4 per wave). gpart[256][64].
// ---------------------------------------------------------------------------
__global__ __launch_bounds__(512) void k_ep2(const float* __restrict__ num2p,
                                             const float* __restrict__ W22,
                                             const float* __restrict__ b22,
                                             float* __restrict__ gpart) {
    __shared__ float w22sh[32 * 64];
    __shared__ float zsh[8][32];
    __shared__ float gsh[8][64];
    const int tid = threadIdx.x, wv = tid >> 6, lane = tid & 63;
    ((float4*)w22sh)[tid] = ((const float4*)W22)[tid];
    const float bb = b22[lane];
    __syncthreads();
    float greg = 0.f;
    for (int it = 0; it < 4; ++it) {
        const int row = blockIdx.x * 32 + wv * 4 + it;
        float val = 0.f;
        if (lane < 33) {
#pragma unroll
            for (int sp = 0; sp < 8; ++sp)
                val += num2p[((size_t)sp * NN + row) * 48 + lane];
        }
        float den = __shfl(val, 32);
        if (lane < 32) zsh[wv][lane] = val / den;
        __builtin_amdgcn_wave_barrier();
        const float4* zv = (const float4*)&zsh[wv][0];
        float o0 = 0.f, o1 = 0.f;
#pragma unroll 4
        for (int c4 = 0; c4 < 8; ++c4) {
            float4 z4 = zv[c4];
            const int c = c4 * 4;
            o0 += z4.x * w22sh[(c + 0) * 64 + lane] + z4.y * w22sh[(c + 1) * 64 + lane];
            o1 += z4.z * w22sh[(c + 2) * 64 + lane] + z4.w * w22sh[(c + 3) * 64 + lane];
        }
        greg += elu_f(bb + o0 + o1);
        __builtin_amdgcn_wave_barrier();
    }
    gsh[wv][lane] = greg;
    __syncthreads();
    if (tid < 64) {
        float s = 0.f;
#pragma unroll
        for (int w = 0; w < 8; ++w) s += gsh[w][tid];
        gpart[(size_t)blockIdx.x * 64 + tid] = s;
    }
}

// ---------------------------------------------------------------------------
// K7: mean + MLP head. gpart is 256 rows (64 KB).
// ---------------------------------------------------------------------------
__global__ __launch_bounds__(256) void k_head(const float* __restrict__ gpart,
                                              const float* __restrict__ M1,
                                              const float* __restrict__ bm1,
                                              const float* __restrict__ M2,
                                              const float* __restrict__ bm2,
                                              float* __restrict__ outp) {
    __shared__ float part[4][64];
    __shared__ float gsh[64];
    __shared__ float hsh[64];
    const int tid = threadIdx.x, col = tid & 63, p = tid >> 6;
    float s = 0.f;
    for (int b = p * 64; b < p * 64 + 64; ++b)
        s += gpart[(size_t)b * 64 + col];
    part[p][col] = s;
    __syncthreads();
    if (tid < 64)
        gsh[tid] = (part[0][tid] + part[1][tid] + part[2][tid] + part[3][tid])
                   * (1.0f / 8192.0f);
    __syncthreads();
    if (tid < 64) {
        float h = bm1[tid];
        for (int c = 0; c < 64; ++c) h += gsh[c] * M1[c * 64 + tid];
        hsh[tid] = h > 0.f ? h : 0.f;
    }
    __syncthreads();
    if (tid < 2) {
        float o = bm2[tid];
        for (int j = 0; j < 64; ++j) o += hsh[j] * M2[j * 2 + tid];
        outp[tid] = o;
    }
}

// ---------------------------------------------------------------------------
extern "C" void kernel_launch(void* const* d_in, const int* in_sizes, int n_in,
                              void* d_out, int out_size, void* d_ws, size_t ws_size,
                              hipStream_t stream) {
    const float* X   = (const float*)d_in[0];
    const int*   A   = (const int*)  d_in[1];
    const float* W1  = (const float*)d_in[2];
    const float* a1  = (const float*)d_in[3];
    const float* W21 = (const float*)d_in[4];
    const float* b21 = (const float*)d_in[5];
    const float* Wg2 = (const float*)d_in[6];
    const float* a2  = (const float*)d_in[7];
    const float* W22 = (const float*)d_in[8];
    const float* b22 = (const float*)d_in[9];
    const float* M1  = (const float*)d_in[10];
    const float* bm1 = (const float*)d_in[11];
    const float* M2  = (const float*)d_in[12];
    const float* bm2 = (const float*)d_in[13];
    float* out = (float*)d_out;

    char* ws = (char*)d_ws;
    unsigned int* Wbits = (unsigned int*)(ws + OFF_WBITS);
    unsigned int* Gt1h  = (unsigned int*)(ws + OFF_GT1H);
    unsigned int* Gt1l  = (unsigned int*)(ws + OFF_GT1L);
    unsigned int* Gt2h  = (unsigned int*)(ws + OFF_GT2H);
    unsigned int* Gt2l  = (unsigned int*)(ws + OFF_GT2L);
    float* Dp    = (float*)(ws + OFF_DP);
    float* gpart = (float*)(ws + OFF_GPART);
    float* nump  = (float*)(ws + OFF_NUMP);

    k_xw1m  <<<dim3(128, 4), 256, 0, stream>>>(X, W1, Dp);
    k_xcomb <<<256, 256, 0, stream>>>(Dp, a1, Gt1h, Gt1l);
    k_attn1f<<<dim3(128, 8), 320, 0, stream>>>(A, Gt1h, Gt1l, Wbits, nump);
    k_ep1   <<<1024, 256, 0, stream>>>(nump, W21, b21, Wg2, a2, Gt2h, Gt2l);
    k_attn2 <<<dim3(128, 8), 256, 0, stream>>>(Wbits, Gt2h, Gt2l, nump);
    k_ep2   <<<256, 512, 0, stream>>>(nump, W22, b22, gpart);
    k_head  <<<1, 256, 0, stream>>>(gpart, M1, bm1, M2, bm2, out);
}